// Round 1
// baseline (1278.957 us; speedup 1.0000x reference)
//
#include <hip/hip_runtime.h>

#define B_   8
#define CIN  256
#define H_   128
#define W_   128
#define HO   64
#define WO   64
#define CO_  256
#define NEG  0.2f

// ws layout (float elements):
//  off : [8][18][64][64]  @ 0         (589824)
//  wt  : [9][256][256]    @ 589824    (589824)   wt[k][c][o] = w_def[o][c][k]
//  w1t : [256][256]       @ 1179648   (65536)    w1t[c][o]   = w_1x1[o][c]
//  y1  : [8][256][64][64] @ 1245184   (8388608)
#define OFF_OFS 0
#define WT_OFS  589824
#define W1T_OFS 1179648
#define Y1_OFS  1245184

__device__ __forceinline__ float lrelu(float v) { return v >= 0.f ? v : NEG * v; }

// ---------------- weight transposes (one-time, tiny) ----------------
__global__ __launch_bounds__(256) void transpose_w(
    const float* __restrict__ wdef, const float* __restrict__ w1,
    float* __restrict__ wt, float* __restrict__ w1t)
{
    int i = blockIdx.x * 256 + threadIdx.x;
    if (i < 9 * 256 * 256) {
        int o = i & 255;
        int c = (i >> 8) & 255;
        int k = i >> 16;
        wt[i] = wdef[((size_t)o * 256 + c) * 9 + k];
    }
    if (i < 256 * 256) {
        w1t[i] = w1[(size_t)(i & 255) * 256 + (i >> 8)];
    }
}

// ---------------- offset conv: 3x3 stride2 pad1, 18 out channels ----------------
__global__ __launch_bounds__(256) void offconv(
    const float* __restrict__ x, const float* __restrict__ w_off,
    float* __restrict__ off)
{
    int blk = blockIdx.x;
    int b  = blk >> 6;
    int ho = blk & 63;
    int t  = threadIdx.x;
    int wo  = t & 63;
    int cog = t >> 6;          // 0..3, uniform per wave

    float acc[5] = {0.f, 0.f, 0.f, 0.f, 0.f};
    const float* xb = x + (size_t)b * CIN * H_ * W_;

    for (int ci = 0; ci < CIN; ++ci) {
        const float* xp = xb + (size_t)ci * (H_ * W_);
        float xv[9];
#pragma unroll
        for (int ky = 0; ky < 3; ++ky) {
            int y = ho * 2 - 1 + ky;
            bool vy = (unsigned)y < (unsigned)H_;
#pragma unroll
            for (int kx = 0; kx < 3; ++kx) {
                int xc = wo * 2 - 1 + kx;
                xv[ky * 3 + kx] = (vy && (unsigned)xc < (unsigned)W_) ? xp[y * W_ + xc] : 0.f;
            }
        }
#pragma unroll
        for (int j = 0; j < 5; ++j) {
            int co = cog + (j << 2);
            if (co < 18) {
                const float* wp = w_off + ((size_t)co * CIN + ci) * 9;
#pragma unroll
                for (int q = 0; q < 9; ++q) acc[j] += xv[q] * wp[q];
            }
        }
    }
#pragma unroll
    for (int j = 0; j < 5; ++j) {
        int co = cog + (j << 2);
        if (co < 18)
            off[(((size_t)b * 18 + co) * HO + ho) * WO + wo] = acc[j];
    }
}

// ---------------- deformable conv as fused sample+GEMM ----------------
// block = (b, ho): 64 pixels x 256 co, K-loop over 9 taps x 8 chunks of 32 channels
__global__ __launch_bounds__(256) void deform_gemm(
    const float* __restrict__ x, const float* __restrict__ off,
    const float* __restrict__ wt, float* __restrict__ yout)
{
    __shared__ __align__(16) float samp[32][64];    // [cc][pix]
    __shared__ __align__(16) float wtile[32][256];  // [cc][co]
    __shared__ int   lofs[64][4];
    __shared__ float lw[64][4];

    int blk = blockIdx.x;
    int b  = blk >> 6;
    int ho = blk & 63;
    int t  = threadIdx.x;

    int pix = t & 63;
    int ccb = t >> 6;      // 0..3
    int pg  = t & 7;       // pixel group -> pixels pg*8..pg*8+7
    int cg  = t >> 3;      // co group   -> co cg*8..cg*8+7

    float acc[8][8];
#pragma unroll
    for (int i = 0; i < 8; ++i)
#pragma unroll
        for (int j = 0; j < 8; ++j) acc[i][j] = 0.f;

    const float* xb = x + (size_t)b * CIN * H_ * W_;

    for (int k = 0; k < 9; ++k) {
        int ky = k / 3, kx = k % 3;
        if (t < 64) {
            int wo = t;
            float dy = off[(((size_t)b * 18 + 2 * k    ) * HO + ho) * WO + wo];
            float dx = off[(((size_t)b * 18 + 2 * k + 1) * HO + ho) * WO + wo];
            float py = (float)(ho * 2 - 1 + ky) + dy;
            float px = (float)(wo * 2 - 1 + kx) + dx;
            float y0f = floorf(py), x0f = floorf(px);
            int y0 = (int)y0f, x0i = (int)x0f;
            float wy1 = py - y0f, wx1 = px - x0f;
            float wy0 = 1.f - wy1, wx0 = 1.f - wx1;
            int y1i = y0 + 1, x1i = x0i + 1;
            bool vy0 = (unsigned)y0  < (unsigned)H_;
            bool vy1 = (unsigned)y1i < (unsigned)H_;
            bool vx0 = (unsigned)x0i < (unsigned)W_;
            bool vx1 = (unsigned)x1i < (unsigned)W_;
            int yc0 = min(max(y0, 0), H_ - 1), yc1 = min(max(y1i, 0), H_ - 1);
            int xc0 = min(max(x0i, 0), W_ - 1), xc1 = min(max(x1i, 0), W_ - 1);
            lofs[wo][0] = yc0 * W_ + xc0;
            lofs[wo][1] = yc0 * W_ + xc1;
            lofs[wo][2] = yc1 * W_ + xc0;
            lofs[wo][3] = yc1 * W_ + xc1;
            lw[wo][0] = (vy0 && vx0) ? wy0 * wx0 : 0.f;
            lw[wo][1] = (vy0 && vx1) ? wy0 * wx1 : 0.f;
            lw[wo][2] = (vy1 && vx0) ? wy1 * wx0 : 0.f;
            lw[wo][3] = (vy1 && vx1) ? wy1 * wx1 : 0.f;
        }
        __syncthreads();
        int   o00 = lofs[pix][0], o01 = lofs[pix][1], o10 = lofs[pix][2], o11 = lofs[pix][3];
        float f00 = lw[pix][0],   f01 = lw[pix][1],   f10 = lw[pix][2],   f11 = lw[pix][3];

        for (int c0 = 0; c0 < CIN; c0 += 32) {
            // stage weight tile [32][256] from wt[k][c0+cc][o] (coalesced)
#pragma unroll
            for (int i = 0; i < 8; ++i) {
                int idx4 = t + i * 256;
                int cc = idx4 >> 6;
                int o4 = (idx4 & 63) << 2;
                *(float4*)&wtile[cc][o4] =
                    *(const float4*)&wt[((size_t)k * 256 + c0 + cc) * 256 + o4];
            }
            // sample 32cc x 64pix (8 samples per thread)
#pragma unroll
            for (int s = 0; s < 8; ++s) {
                int cc = ccb + 4 * s;
                const float* xq = xb + (size_t)(c0 + cc) * (H_ * W_);
                samp[cc][pix] = xq[o00] * f00 + xq[o01] * f01 + xq[o10] * f10 + xq[o11] * f11;
            }
            __syncthreads();
            // 8x8 register outer product
#pragma unroll 8
            for (int cc = 0; cc < 32; ++cc) {
                float4 sa = *(const float4*)&samp[cc][pg * 8];
                float4 sb = *(const float4*)&samp[cc][pg * 8 + 4];
                float4 wa = *(const float4*)&wtile[cc][cg * 8];
                float4 wb = *(const float4*)&wtile[cc][cg * 8 + 4];
                float s8[8] = {sa.x, sa.y, sa.z, sa.w, sb.x, sb.y, sb.z, sb.w};
                float w8[8] = {wa.x, wa.y, wa.z, wa.w, wb.x, wb.y, wb.z, wb.w};
#pragma unroll
                for (int i = 0; i < 8; ++i)
#pragma unroll
                    for (int j = 0; j < 8; ++j) acc[i][j] += s8[i] * w8[j];
            }
            __syncthreads();
        }
    }
    // write y1 with leaky relu
#pragma unroll
    for (int j = 0; j < 8; ++j) {
        int co = cg * 8 + j;
        float* dst = yout + (((size_t)b * CO_ + co) * HO + ho) * WO + pg * 8;
        float4 v0, v1;
        v0.x = lrelu(acc[0][j]); v0.y = lrelu(acc[1][j]);
        v0.z = lrelu(acc[2][j]); v0.w = lrelu(acc[3][j]);
        v1.x = lrelu(acc[4][j]); v1.y = lrelu(acc[5][j]);
        v1.z = lrelu(acc[6][j]); v1.w = lrelu(acc[7][j]);
        *(float4*)&dst[0] = v0;
        *(float4*)&dst[4] = v1;
    }
}

// ---------------- 1x1 conv (pre-norm result straight into d_out) ----------------
__global__ __launch_bounds__(256) void conv1x1(
    const float* __restrict__ y1, const float* __restrict__ w1t,
    float* __restrict__ out)
{
    __shared__ __align__(16) float ytile[32][64];
    __shared__ __align__(16) float wtile[32][256];

    int blk = blockIdx.x;
    int b  = blk >> 6;
    int ho = blk & 63;
    int t  = threadIdx.x;
    int pg = t & 7;
    int cg = t >> 3;

    float acc[8][8];
#pragma unroll
    for (int i = 0; i < 8; ++i)
#pragma unroll
        for (int j = 0; j < 8; ++j) acc[i][j] = 0.f;

    for (int c0 = 0; c0 < 256; c0 += 32) {
#pragma unroll
        for (int i = 0; i < 8; ++i) {
            int idx4 = t + i * 256;
            int cc = idx4 >> 6;
            int o4 = (idx4 & 63) << 2;
            *(float4*)&wtile[cc][o4] = *(const float4*)&w1t[(size_t)(c0 + cc) * 256 + o4];
        }
#pragma unroll
        for (int i = 0; i < 2; ++i) {
            int idx4 = t + i * 256;
            int cc = idx4 >> 4;
            int p4 = (idx4 & 15) << 2;
            *(float4*)&ytile[cc][p4] =
                *(const float4*)&y1[(((size_t)b * 256 + c0 + cc) * HO + ho) * WO + p4];
        }
        __syncthreads();
#pragma unroll 8
        for (int cc = 0; cc < 32; ++cc) {
            float4 sa = *(const float4*)&ytile[cc][pg * 8];
            float4 sb = *(const float4*)&ytile[cc][pg * 8 + 4];
            float4 wa = *(const float4*)&wtile[cc][cg * 8];
            float4 wb = *(const float4*)&wtile[cc][cg * 8 + 4];
            float s8[8] = {sa.x, sa.y, sa.z, sa.w, sb.x, sb.y, sb.z, sb.w};
            float w8[8] = {wa.x, wa.y, wa.z, wa.w, wb.x, wb.y, wb.z, wb.w};
#pragma unroll
            for (int i = 0; i < 8; ++i)
#pragma unroll
                for (int j = 0; j < 8; ++j) acc[i][j] += s8[i] * w8[j];
        }
        __syncthreads();
    }
#pragma unroll
    for (int j = 0; j < 8; ++j) {
        int co = cg * 8 + j;
        float* dst = out + (((size_t)b * CO_ + co) * HO + ho) * WO + pg * 8;
        float4 v0, v1;
        v0.x = acc[0][j]; v0.y = acc[1][j]; v0.z = acc[2][j]; v0.w = acc[3][j];
        v1.x = acc[4][j]; v1.y = acc[5][j]; v1.z = acc[6][j]; v1.w = acc[7][j];
        *(float4*)&dst[0] = v0;
        *(float4*)&dst[4] = v1;
    }
}

// ---------------- instance norm + leaky, in place on d_out ----------------
__global__ __launch_bounds__(256) void instnorm(float* __restrict__ out)
{
    int bc = blockIdx.x;            // b*256 + c
    float* p = out + (size_t)bc * 4096;
    int t = threadIdx.x;

    float4 v[4];
    float s1 = 0.f, s2 = 0.f;
#pragma unroll
    for (int i = 0; i < 4; ++i) {
        v[i] = *(const float4*)&p[(t + i * 256) * 4];
        s1 += v[i].x + v[i].y + v[i].z + v[i].w;
        s2 += v[i].x * v[i].x + v[i].y * v[i].y + v[i].z * v[i].z + v[i].w * v[i].w;
    }
#pragma unroll
    for (int o = 32; o > 0; o >>= 1) {
        s1 += __shfl_down(s1, o);
        s2 += __shfl_down(s2, o);
    }
    __shared__ float rs[8];
    __shared__ float mb[2];
    int wave = t >> 6;
    if ((t & 63) == 0) { rs[wave] = s1; rs[4 + wave] = s2; }
    __syncthreads();
    if (t == 0) {
        float a = rs[0] + rs[1] + rs[2] + rs[3];
        float q = rs[4] + rs[5] + rs[6] + rs[7];
        float mean = a * (1.f / 4096.f);
        float var  = q * (1.f / 4096.f) - mean * mean;
        mb[0] = mean;
        mb[1] = rsqrtf(var + 1e-5f);
    }
    __syncthreads();
    float mean = mb[0], inv = mb[1];
#pragma unroll
    for (int i = 0; i < 4; ++i) {
        float4 u = v[i];
        u.x = lrelu((u.x - mean) * inv);
        u.y = lrelu((u.y - mean) * inv);
        u.z = lrelu((u.z - mean) * inv);
        u.w = lrelu((u.w - mean) * inv);
        *(float4*)&p[(t + i * 256) * 4] = u;
    }
}

extern "C" void kernel_launch(void* const* d_in, const int* in_sizes, int n_in,
                              void* d_out, int out_size, void* d_ws, size_t ws_size,
                              hipStream_t stream)
{
    const float* x     = (const float*)d_in[0];
    const float* w_off = (const float*)d_in[1];
    const float* w_def = (const float*)d_in[2];
    const float* w1    = (const float*)d_in[3];
    float* out = (float*)d_out;
    float* ws  = (float*)d_ws;

    float* off = ws + OFF_OFS;
    float* wt  = ws + WT_OFS;
    float* w1t = ws + W1T_OFS;
    float* y1  = ws + Y1_OFS;

    hipLaunchKernelGGL(transpose_w, dim3(2304), dim3(256), 0, stream, w_def, w1, wt, w1t);
    hipLaunchKernelGGL(offconv,     dim3(512),  dim3(256), 0, stream, x, w_off, off);
    hipLaunchKernelGGL(deform_gemm, dim3(512),  dim3(256), 0, stream, x, off, wt, y1);
    hipLaunchKernelGGL(conv1x1,     dim3(512),  dim3(256), 0, stream, y1, w1t, out);
    hipLaunchKernelGGL(instnorm,    dim3(2048), dim3(256), 0, stream, out);
}

// Round 2
// 659.343 us; speedup vs baseline: 1.9397x; 1.9397x over previous
//
#include <hip/hip_runtime.h>

#define B_   8
#define CIN  256
#define H_   128
#define W_   128
#define HO   64
#define WO   64
#define CO_  256
#define NEG  0.2f

typedef __attribute__((ext_vector_type(8))) short bf16x8;
typedef __attribute__((ext_vector_type(4))) float f32x4;
typedef unsigned short u16;

// ws layout (float slots):
//  off    : [8][18][64][64] f32            @ 0        (589824)
//  wdefbf : [9][8][256][32] bf16           @ 589824   (589824 elems = 294912 slots)
//  w1bf   : [256][256] bf16                @ 884736   (65536 elems = 32768 slots)
//  y1p    : [8][64][64][256] bf16          @ 917504   (8388608 elems = 4194304 slots)
#define OFF_OFS   0
#define WDEF_OFS  589824
#define W1_OFS    884736
#define Y1_OFS    917504

__device__ __forceinline__ float lrelu(float v) { return v >= 0.f ? v : NEG * v; }

__device__ __forceinline__ u16 f2bf(float f) {
    unsigned u = __float_as_uint(f);
    u += 0x7FFFu + ((u >> 16) & 1u);   // RNE
    return (u16)(u >> 16);
}

__device__ __forceinline__ void gld16(const void* g, void* l) {
    __builtin_amdgcn_global_load_lds((const __attribute__((address_space(1))) unsigned*)g,
                                     (__attribute__((address_space(3))) unsigned*)l, 16, 0, 0);
}

// ---------------- one-time weight prep: transpose + bf16 ----------------
__global__ __launch_bounds__(256) void prep(
    const float* __restrict__ wdef, const float* __restrict__ w1,
    u16* __restrict__ wdefbf, u16* __restrict__ w1bf)
{
    int i = blockIdx.x * 256 + threadIdx.x;
    if (i < 9 * 8 * 256 * 32) {
        int cc = i & 31;
        int co = (i >> 5) & 255;
        int ch = (i >> 13) & 7;
        int k  = i >> 16;
        wdefbf[i] = f2bf(wdef[((size_t)co * 256 + ch * 32 + cc) * 9 + k]);
    }
    if (i < 65536) w1bf[i] = f2bf(w1[i]);
}

// ---------------- offset conv: 3x3 stride2 pad1, 18 out channels (fp32) ----------------
__global__ __launch_bounds__(256) void offconv(
    const float* __restrict__ x, const float* __restrict__ w_off,
    float* __restrict__ off)
{
    int blk = blockIdx.x;
    blk = (blk & 7) * 64 + (blk >> 3);   // XCD swizzle: each XCD owns one b
    int b  = blk >> 6;
    int ho = blk & 63;
    int t  = threadIdx.x;
    int wo  = t & 63;
    int cog = t >> 6;

    float acc[5] = {0.f, 0.f, 0.f, 0.f, 0.f};
    const float* xb = x + (size_t)b * CIN * H_ * W_;

    for (int ci = 0; ci < CIN; ++ci) {
        const float* xp = xb + (size_t)ci * (H_ * W_);
        float xv[9];
#pragma unroll
        for (int ky = 0; ky < 3; ++ky) {
            int y = ho * 2 - 1 + ky;
            bool vy = (unsigned)y < (unsigned)H_;
#pragma unroll
            for (int kx = 0; kx < 3; ++kx) {
                int xc = wo * 2 - 1 + kx;
                xv[ky * 3 + kx] = (vy && (unsigned)xc < (unsigned)W_) ? xp[y * W_ + xc] : 0.f;
            }
        }
#pragma unroll
        for (int j = 0; j < 5; ++j) {
            int co = cog + (j << 2);
            if (co < 18) {
                const float* wp = w_off + ((size_t)co * CIN + ci) * 9;
#pragma unroll
                for (int q = 0; q < 9; ++q) acc[j] += xv[q] * wp[q];
            }
        }
    }
#pragma unroll
    for (int j = 0; j < 5; ++j) {
        int co = cog + (j << 2);
        if (co < 18)
            off[(((size_t)b * 18 + co) * HO + ho) * WO + wo] = acc[j];
    }
}

// ---------------- deformable conv: bilinear sample -> bf16 MFMA GEMM ----------------
// block=(b,ho): M=64 pix, N=256 co, K=9*256. 4 waves, wave w: co in [64w,64w+64)
__global__ __launch_bounds__(256) void deform_mfma(
    const float* __restrict__ x, const float* __restrict__ off,
    const u16* __restrict__ wdefbf, u16* __restrict__ y1p)
{
    __shared__ __align__(16) char smem[33792];
    u16*   wtile = (u16*)smem;              // [256][32] bf16, quarter-swizzled
    u16*   samp  = (u16*)(smem + 16384);    // [64][32]  bf16, quarter-swizzled
    int*   lofs  = (int*)(smem + 20480);    // [64][4]
    float* lw    = (float*)(smem + 21504);  // [64][4]
    u16*   outT  = (u16*)smem;              // [64][256] epilogue alias (32KB)

    int blk = blockIdx.x;
    blk = (blk & 7) * 64 + (blk >> 3);      // XCD swizzle
    int b = blk >> 6, ho = blk & 63;
    int t = threadIdx.x;
    int lane = t & 63, w = t >> 6;
    int pix = t & 63;                        // sampler pixel
    int q   = t >> 6;                        // sampler cc-quarter

    f32x4 acc[4][4];
    f32x4 zz = {0.f, 0.f, 0.f, 0.f};
#pragma unroll
    for (int m = 0; m < 4; ++m)
#pragma unroll
        for (int n = 0; n < 4; ++n) acc[m][n] = zz;

    const float* xb = x + (size_t)b * (CIN * H_ * W_);
    int r  = lane & 15;
    int kg = lane >> 4;
    int sA = (pix >> 1) & 3;                 // write-side swizzle sel
    int sR = (r >> 1) & 3;                   // read-side swizzle sel (A rows & B rows)

    for (int k = 0; k < 9; ++k) {
        int ky = k / 3, kx = k - 3 * ky;
        if (t < 64) {
            int wo = t;
            float dy = off[(((size_t)b * 18 + 2 * k    ) * HO + ho) * WO + wo];
            float dx = off[(((size_t)b * 18 + 2 * k + 1) * HO + ho) * WO + wo];
            float py = (float)(ho * 2 - 1 + ky) + dy;
            float px = (float)(wo * 2 - 1 + kx) + dx;
            float y0f = floorf(py), x0f = floorf(px);
            int y0 = (int)y0f, x0i = (int)x0f;
            float wy1 = py - y0f, wx1 = px - x0f;
            float wy0 = 1.f - wy1, wx0 = 1.f - wx1;
            int y1i = y0 + 1, x1i = x0i + 1;
            bool vy0 = (unsigned)y0  < (unsigned)H_;
            bool vy1 = (unsigned)y1i < (unsigned)H_;
            bool vx0 = (unsigned)x0i < (unsigned)W_;
            bool vx1 = (unsigned)x1i < (unsigned)W_;
            int yc0 = min(max(y0, 0), H_ - 1), yc1 = min(max(y1i, 0), H_ - 1);
            int xc0 = min(max(x0i, 0), W_ - 1), xc1 = min(max(x1i, 0), W_ - 1);
            lofs[wo * 4 + 0] = yc0 * W_ + xc0;
            lofs[wo * 4 + 1] = yc0 * W_ + xc1;
            lofs[wo * 4 + 2] = yc1 * W_ + xc0;
            lofs[wo * 4 + 3] = yc1 * W_ + xc1;
            lw[wo * 4 + 0] = (vy0 && vx0) ? wy0 * wx0 : 0.f;
            lw[wo * 4 + 1] = (vy0 && vx1) ? wy0 * wx1 : 0.f;
            lw[wo * 4 + 2] = (vy1 && vx0) ? wy1 * wx0 : 0.f;
            lw[wo * 4 + 3] = (vy1 && vx1) ? wy1 * wx1 : 0.f;
        }
        __syncthreads();
        int   o00 = lofs[pix * 4 + 0], o01 = lofs[pix * 4 + 1];
        int   o10 = lofs[pix * 4 + 2], o11 = lofs[pix * 4 + 3];
        float f00 = lw[pix * 4 + 0],   f01 = lw[pix * 4 + 1];
        float f10 = lw[pix * 4 + 2],   f11 = lw[pix * 4 + 3];

        const u16* wk = wdefbf + ((size_t)k << 16);   // k*8*8192
        for (int ch = 0; ch < 8; ++ch) {
            // stage weight tile [256co][32cc] with baked read-swizzle (per-lane src addr)
            const u16* wsrc = wk + (ch << 13);
#pragma unroll
            for (int p = 0; p < 4; ++p) {
                int slot = p * 256 + t;
                int co = slot >> 2, qq = slot & 3;
                gld16(wsrc + co * 32 + ((qq ^ ((co >> 1) & 3)) << 3),
                      smem + p * 4096 + (t >> 6) * 1024);
            }
            // bilinear-sample 8 channels for this pixel, pack bf16, swizzled LDS write
            bf16x8 sv;
#pragma unroll
            for (int j = 0; j < 8; ++j) {
                int c = ch * 32 + q * 8 + j;
                const float* xq = xb + (size_t)c * (H_ * W_);
                float v = xq[o00] * f00 + xq[o01] * f01 + xq[o10] * f10 + xq[o11] * f11;
                sv[j] = (short)f2bf(v);
            }
            *(bf16x8*)(samp + pix * 32 + ((q ^ sA) << 3)) = sv;
            __syncthreads();

            // fragments + 16 MFMA
            bf16x8 af[4], bfr[4];
#pragma unroll
            for (int m = 0; m < 4; ++m)
                af[m] = *(bf16x8*)(samp + (m * 16 + r) * 32 + ((kg ^ sR) << 3));
#pragma unroll
            for (int n = 0; n < 4; ++n)
                bfr[n] = *(bf16x8*)(wtile + (w * 64 + n * 16 + r) * 32 + ((kg ^ sR) << 3));
#pragma unroll
            for (int m = 0; m < 4; ++m)
#pragma unroll
                for (int n = 0; n < 4; ++n)
                    acc[m][n] = __builtin_amdgcn_mfma_f32_16x16x32_bf16(af[m], bfr[n], acc[m][n], 0, 0, 0);
            __syncthreads();
        }
    }

    // epilogue: leaky-relu, transpose via LDS to [pix][c] bf16, linear copy out
    int rg = lane >> 4;
#pragma unroll
    for (int m = 0; m < 4; ++m)
#pragma unroll
        for (int n = 0; n < 4; ++n) {
            int co = w * 64 + n * 16 + r;
#pragma unroll
            for (int j = 0; j < 4; ++j) {
                int prow = m * 16 + rg * 4 + j;
                outT[prow * 256 + co] = f2bf(lrelu(acc[m][n][j]));
            }
        }
    __syncthreads();
    u16* dst = y1p + (size_t)(b * 64 + ho) * 16384;
#pragma unroll
    for (int j = 0; j < 8; ++j)
        *(int4*)((char*)dst + j * 4096 + t * 16) = *(int4*)(smem + j * 4096 + t * 16);
}

// ---------------- 1x1 conv: bf16 MFMA, M=64 pix, N=256 o, K=256 c ----------------
__global__ __launch_bounds__(256) void conv1x1_mfma(
    const u16* __restrict__ y1p, const u16* __restrict__ w1bf,
    float* __restrict__ out)
{
    __shared__ __align__(16) char smem[20480];
    u16* btile = (u16*)smem;              // [256 o][32 c]
    u16* atile = (u16*)(smem + 16384);    // [64 pix][32 c]

    int blk = blockIdx.x;
    blk = (blk & 7) * 64 + (blk >> 3);
    int b = blk >> 6, ho = blk & 63;
    int t = threadIdx.x, lane = t & 63, w = t >> 6;
    int r = lane & 15, kg = lane >> 4;
    int sR = (r >> 1) & 3;

    f32x4 acc[4][4];
    f32x4 zz = {0.f, 0.f, 0.f, 0.f};
#pragma unroll
    for (int m = 0; m < 4; ++m)
#pragma unroll
        for (int n = 0; n < 4; ++n) acc[m][n] = zz;

    const u16* abase = y1p + (size_t)(b * 64 + ho) * 16384;

    for (int ch = 0; ch < 8; ++ch) {
#pragma unroll
        for (int p = 0; p < 4; ++p) {
            int slot = p * 256 + t;
            int o = slot >> 2, qq = slot & 3;
            gld16(w1bf + o * 256 + ch * 32 + ((qq ^ ((o >> 1) & 3)) << 3),
                  smem + p * 4096 + (t >> 6) * 1024);
        }
        {
            int pix = t >> 2, qq = t & 3;
            gld16(abase + pix * 256 + ch * 32 + ((qq ^ ((pix >> 1) & 3)) << 3),
                  smem + 16384 + (t >> 6) * 1024);
        }
        __syncthreads();
        bf16x8 af[4], bfr[4];
#pragma unroll
        for (int m = 0; m < 4; ++m)
            af[m] = *(bf16x8*)(atile + (m * 16 + r) * 32 + ((kg ^ sR) << 3));
#pragma unroll
        for (int n = 0; n < 4; ++n)
            bfr[n] = *(bf16x8*)(btile + (w * 64 + n * 16 + r) * 32 + ((kg ^ sR) << 3));
#pragma unroll
        for (int m = 0; m < 4; ++m)
#pragma unroll
            for (int n = 0; n < 4; ++n)
                acc[m][n] = __builtin_amdgcn_mfma_f32_16x16x32_bf16(af[m], bfr[n], acc[m][n], 0, 0, 0);
        __syncthreads();
    }

    int rg = lane >> 4;
#pragma unroll
    for (int m = 0; m < 4; ++m)
#pragma unroll
        for (int n = 0; n < 4; ++n) {
            int o = w * 64 + n * 16 + r;
            int pix0 = m * 16 + rg * 4;
            float4 v;
            v.x = acc[m][n][0]; v.y = acc[m][n][1];
            v.z = acc[m][n][2]; v.w = acc[m][n][3];
            *(float4*)(out + ((size_t)(b * 256 + o) * 64 + ho) * 64 + pix0) = v;
        }
}

// ---------------- instance norm + leaky, in place on d_out ----------------
__global__ __launch_bounds__(256) void instnorm(float* __restrict__ out)
{
    int bc = blockIdx.x;
    float* p = out + (size_t)bc * 4096;
    int t = threadIdx.x;

    float4 v[4];
    float s1 = 0.f, s2 = 0.f;
#pragma unroll
    for (int i = 0; i < 4; ++i) {
        v[i] = *(const float4*)&p[(t + i * 256) * 4];
        s1 += v[i].x + v[i].y + v[i].z + v[i].w;
        s2 += v[i].x * v[i].x + v[i].y * v[i].y + v[i].z * v[i].z + v[i].w * v[i].w;
    }
#pragma unroll
    for (int o = 32; o > 0; o >>= 1) {
        s1 += __shfl_down(s1, o);
        s2 += __shfl_down(s2, o);
    }
    __shared__ float rs[8];
    __shared__ float mb[2];
    int wave = t >> 6;
    if ((t & 63) == 0) { rs[wave] = s1; rs[4 + wave] = s2; }
    __syncthreads();
    if (t == 0) {
        float a = rs[0] + rs[1] + rs[2] + rs[3];
        float qq = rs[4] + rs[5] + rs[6] + rs[7];
        float mean = a * (1.f / 4096.f);
        float var  = qq * (1.f / 4096.f) - mean * mean;
        mb[0] = mean;
        mb[1] = rsqrtf(var + 1e-5f);
    }
    __syncthreads();
    float mean = mb[0], inv = mb[1];
#pragma unroll
    for (int i = 0; i < 4; ++i) {
        float4 u = v[i];
        u.x = lrelu((u.x - mean) * inv);
        u.y = lrelu((u.y - mean) * inv);
        u.z = lrelu((u.z - mean) * inv);
        u.w = lrelu((u.w - mean) * inv);
        *(float4*)&p[(t + i * 256) * 4] = u;
    }
}

extern "C" void kernel_launch(void* const* d_in, const int* in_sizes, int n_in,
                              void* d_out, int out_size, void* d_ws, size_t ws_size,
                              hipStream_t stream)
{
    const float* x     = (const float*)d_in[0];
    const float* w_off = (const float*)d_in[1];
    const float* w_def = (const float*)d_in[2];
    const float* w1    = (const float*)d_in[3];
    float* out = (float*)d_out;
    float* ws  = (float*)d_ws;

    float* off    = ws + OFF_OFS;
    u16*   wdefbf = (u16*)(ws + WDEF_OFS);
    u16*   w1bf   = (u16*)(ws + W1_OFS);
    u16*   y1p    = (u16*)(ws + Y1_OFS);

    hipLaunchKernelGGL(prep,         dim3(2304), dim3(256), 0, stream, w_def, w1, wdefbf, w1bf);
    hipLaunchKernelGGL(offconv,      dim3(512),  dim3(256), 0, stream, x, w_off, off);
    hipLaunchKernelGGL(deform_mfma,  dim3(512),  dim3(256), 0, stream, x, off, wdefbf, y1p);
    hipLaunchKernelGGL(conv1x1_mfma, dim3(512),  dim3(256), 0, stream, y1p, w1bf, out);
    hipLaunchKernelGGL(instnorm,     dim3(2048), dim3(256), 0, stream, out);
}

// Round 3
// 592.203 us; speedup vs baseline: 2.1597x; 1.1134x over previous
//
#include <hip/hip_runtime.h>

#define B_   8
#define CIN  256
#define H_   128
#define W_   128
#define HO   64
#define WO   64
#define CO_  256
#define NEG  0.2f

typedef __attribute__((ext_vector_type(8))) short bf16x8;
typedef __attribute__((ext_vector_type(4))) float f32x4;
typedef unsigned short u16;

// ws layout (float slots):
//  off    : [8][18][64][64] f32            @ 0        (589824)
//  wdefbf : [9][8][256][32] bf16           @ 589824   (294912 slots)
//  w1bf   : [256][256] bf16                @ 884736   (32768 slots)
//  y1p    : [8][64][64][256] bf16          @ 917504   (4194304 slots)
//  part   : [4][8][18][64][64] f32         @ 917504   (2359296 slots, ALIASES y1p;
//                                                      dead before deform writes y1p)
#define OFF_OFS   0
#define WDEF_OFS  589824
#define W1_OFS    884736
#define Y1_OFS    917504
#define PART_OFS  917504

__device__ __forceinline__ float lrelu(float v) { return v >= 0.f ? v : NEG * v; }

__device__ __forceinline__ u16 f2bf(float f) {
    unsigned u = __float_as_uint(f);
    u += 0x7FFFu + ((u >> 16) & 1u);   // RNE
    return (u16)(u >> 16);
}

__device__ __forceinline__ void gld16(const void* g, void* l) {
    __builtin_amdgcn_global_load_lds((const __attribute__((address_space(1))) unsigned*)g,
                                     (__attribute__((address_space(3))) unsigned*)l, 16, 0, 0);
}

// ---------------- one-time weight prep: transpose + bf16 ----------------
__global__ __launch_bounds__(256) void prep(
    const float* __restrict__ wdef, const float* __restrict__ w1,
    u16* __restrict__ wdefbf, u16* __restrict__ w1bf)
{
    int i = blockIdx.x * 256 + threadIdx.x;
    if (i < 9 * 8 * 256 * 32) {
        int cc = i & 31;
        int co = (i >> 5) & 255;
        int ch = (i >> 13) & 7;
        int k  = i >> 16;
        wdefbf[i] = f2bf(wdef[((size_t)co * 256 + ch * 32 + cc) * 9 + k]);
    }
    if (i < 65536) w1bf[i] = f2bf(w1[i]);
}

// ---------------- offset conv, ci-split 4-way for occupancy ----------------
// grid 2048: (b, g, ho); each block reduces ci in [g*64, g*64+64)
__global__ __launch_bounds__(256) void offconv_partial(
    const float* __restrict__ x, const float* __restrict__ w_off,
    float* __restrict__ part)
{
    int bid = blockIdx.x;
    int swz = (bid & 7) * 256 + (bid >> 3);   // XCD owns one b (all g, all ho)
    int b  = swz >> 8;
    int g  = (swz >> 6) & 3;
    int ho = swz & 63;
    int t  = threadIdx.x;
    int wo  = t & 63;
    int cog = t >> 6;

    float acc[5] = {0.f, 0.f, 0.f, 0.f, 0.f};
    const float* xb = x + (size_t)b * CIN * H_ * W_;

    int ci0 = g * 64;
    for (int ci = ci0; ci < ci0 + 64; ++ci) {
        const float* xp = xb + (size_t)ci * (H_ * W_);
        float xv[9];
#pragma unroll
        for (int ky = 0; ky < 3; ++ky) {
            int y = ho * 2 - 1 + ky;
            bool vy = (unsigned)y < (unsigned)H_;
#pragma unroll
            for (int kx = 0; kx < 3; ++kx) {
                int xc = wo * 2 - 1 + kx;
                xv[ky * 3 + kx] = (vy && (unsigned)xc < (unsigned)W_) ? xp[y * W_ + xc] : 0.f;
            }
        }
#pragma unroll
        for (int j = 0; j < 5; ++j) {
            int co = cog + (j << 2);
            if (co < 18) {
                const float* wp = w_off + ((size_t)co * CIN + ci) * 9;
#pragma unroll
                for (int q = 0; q < 9; ++q) acc[j] += xv[q] * wp[q];
            }
        }
    }
#pragma unroll
    for (int j = 0; j < 5; ++j) {
        int co = cog + (j << 2);
        if (co < 18)
            part[(((size_t)(g * 8 + b) * 18 + co) * HO + ho) * WO + wo] = acc[j];
    }
}

// sum the 4 partials -> off  (589824 floats = 147456 float4)
__global__ __launch_bounds__(256) void reduce_off(
    const float* __restrict__ part, float* __restrict__ off)
{
    int i4 = blockIdx.x * 256 + threadIdx.x;   // float4 index, grid covers 147456
    if (i4 >= 147456) return;
    float4 a = *(const float4*)&part[(size_t)i4 * 4];
    float4 b = *(const float4*)&part[(size_t)i4 * 4 + 589824];
    float4 c = *(const float4*)&part[(size_t)i4 * 4 + 2 * 589824];
    float4 d = *(const float4*)&part[(size_t)i4 * 4 + 3 * 589824];
    float4 o;
    o.x = (a.x + b.x) + (c.x + d.x);
    o.y = (a.y + b.y) + (c.y + d.y);
    o.z = (a.z + b.z) + (c.z + d.z);
    o.w = (a.w + b.w) + (c.w + d.w);
    *(float4*)&off[(size_t)i4 * 4] = o;
}

// ---------------- deformable conv: bilinear sample -> bf16 MFMA GEMM ----------------
__global__ __launch_bounds__(256) void deform_mfma(
    const float* __restrict__ x, const float* __restrict__ off,
    const u16* __restrict__ wdefbf, u16* __restrict__ y1p)
{
    __shared__ __align__(16) char smem[33792];
    u16*   wtile = (u16*)smem;              // [256][32] bf16, quarter-swizzled
    u16*   samp  = (u16*)(smem + 16384);    // [64][32]  bf16, quarter-swizzled
    int*   lofs  = (int*)(smem + 20480);    // [64][4]
    float* lw    = (float*)(smem + 21504);  // [64][4]
    u16*   outT  = (u16*)smem;              // [64][256] epilogue alias (32KB)

    int blk = blockIdx.x;
    blk = (blk & 7) * 64 + (blk >> 3);      // XCD swizzle
    int b = blk >> 6, ho = blk & 63;
    int t = threadIdx.x;
    int lane = t & 63, w = t >> 6;
    int pix = t & 63;
    int q   = t >> 6;

    f32x4 acc[4][4];
    f32x4 zz = {0.f, 0.f, 0.f, 0.f};
#pragma unroll
    for (int m = 0; m < 4; ++m)
#pragma unroll
        for (int n = 0; n < 4; ++n) acc[m][n] = zz;

    const float* xb = x + (size_t)b * (CIN * H_ * W_);
    int r  = lane & 15;
    int kg = lane >> 4;
    int sA = (pix >> 1) & 3;
    int sR = (r >> 1) & 3;

    for (int k = 0; k < 9; ++k) {
        int ky = k / 3, kx = k - 3 * ky;
        if (t < 64) {
            int wo = t;
            float dy = off[(((size_t)b * 18 + 2 * k    ) * HO + ho) * WO + wo];
            float dx = off[(((size_t)b * 18 + 2 * k + 1) * HO + ho) * WO + wo];
            float py = (float)(ho * 2 - 1 + ky) + dy;
            float px = (float)(wo * 2 - 1 + kx) + dx;
            float y0f = floorf(py), x0f = floorf(px);
            int y0 = (int)y0f, x0i = (int)x0f;
            float wy1 = py - y0f, wx1 = px - x0f;
            float wy0 = 1.f - wy1, wx0 = 1.f - wx1;
            int y1i = y0 + 1, x1i = x0i + 1;
            bool vy0 = (unsigned)y0  < (unsigned)H_;
            bool vy1 = (unsigned)y1i < (unsigned)H_;
            bool vx0 = (unsigned)x0i < (unsigned)W_;
            bool vx1 = (unsigned)x1i < (unsigned)W_;
            int yc0 = min(max(y0, 0), H_ - 1), yc1 = min(max(y1i, 0), H_ - 1);
            int xc0 = min(max(x0i, 0), W_ - 1), xc1 = min(max(x1i, 0), W_ - 1);
            lofs[wo * 4 + 0] = yc0 * W_ + xc0;
            lofs[wo * 4 + 1] = yc0 * W_ + xc1;
            lofs[wo * 4 + 2] = yc1 * W_ + xc0;
            lofs[wo * 4 + 3] = yc1 * W_ + xc1;
            lw[wo * 4 + 0] = (vy0 && vx0) ? wy0 * wx0 : 0.f;
            lw[wo * 4 + 1] = (vy0 && vx1) ? wy0 * wx1 : 0.f;
            lw[wo * 4 + 2] = (vy1 && vx0) ? wy1 * wx0 : 0.f;
            lw[wo * 4 + 3] = (vy1 && vx1) ? wy1 * wx1 : 0.f;
        }
        __syncthreads();
        int   o00 = lofs[pix * 4 + 0], o01 = lofs[pix * 4 + 1];
        int   o10 = lofs[pix * 4 + 2], o11 = lofs[pix * 4 + 3];
        float f00 = lw[pix * 4 + 0],   f01 = lw[pix * 4 + 1];
        float f10 = lw[pix * 4 + 2],   f11 = lw[pix * 4 + 3];

        const u16* wk = wdefbf + ((size_t)k << 16);
        for (int ch = 0; ch < 8; ++ch) {
            const u16* wsrc = wk + (ch << 13);
#pragma unroll
            for (int p = 0; p < 4; ++p) {
                int slot = p * 256 + t;
                int co = slot >> 2, qq = slot & 3;
                gld16(wsrc + co * 32 + ((qq ^ ((co >> 1) & 3)) << 3),
                      smem + p * 4096 + (t >> 6) * 1024);
            }
            bf16x8 sv;
#pragma unroll
            for (int j = 0; j < 8; ++j) {
                int c = ch * 32 + q * 8 + j;
                const float* xq = xb + (size_t)c * (H_ * W_);
                float v = xq[o00] * f00 + xq[o01] * f01 + xq[o10] * f10 + xq[o11] * f11;
                sv[j] = (short)f2bf(v);
            }
            *(bf16x8*)(samp + pix * 32 + ((q ^ sA) << 3)) = sv;
            __syncthreads();

            bf16x8 af[4], bfr[4];
#pragma unroll
            for (int m = 0; m < 4; ++m)
                af[m] = *(bf16x8*)(samp + (m * 16 + r) * 32 + ((kg ^ sR) << 3));
#pragma unroll
            for (int n = 0; n < 4; ++n)
                bfr[n] = *(bf16x8*)(wtile + (w * 64 + n * 16 + r) * 32 + ((kg ^ sR) << 3));
#pragma unroll
            for (int m = 0; m < 4; ++m)
#pragma unroll
                for (int n = 0; n < 4; ++n)
                    acc[m][n] = __builtin_amdgcn_mfma_f32_16x16x32_bf16(af[m], bfr[n], acc[m][n], 0, 0, 0);
            __syncthreads();
        }
    }

    int rg = lane >> 4;
#pragma unroll
    for (int m = 0; m < 4; ++m)
#pragma unroll
        for (int n = 0; n < 4; ++n) {
            int co = w * 64 + n * 16 + r;
#pragma unroll
            for (int j = 0; j < 4; ++j) {
                int prow = m * 16 + rg * 4 + j;
                outT[prow * 256 + co] = f2bf(lrelu(acc[m][n][j]));
            }
        }
    __syncthreads();
    u16* dst = y1p + (size_t)(b * 64 + ho) * 16384;
#pragma unroll
    for (int j = 0; j < 8; ++j)
        *(int4*)((char*)dst + j * 4096 + t * 16) = *(int4*)(smem + j * 4096 + t * 16);
}

// ---------------- 1x1 conv: bf16 MFMA ----------------
__global__ __launch_bounds__(256) void conv1x1_mfma(
    const u16* __restrict__ y1p, const u16* __restrict__ w1bf,
    float* __restrict__ out)
{
    __shared__ __align__(16) char smem[20480];
    u16* btile = (u16*)smem;
    u16* atile = (u16*)(smem + 16384);

    int blk = blockIdx.x;
    blk = (blk & 7) * 64 + (blk >> 3);
    int b = blk >> 6, ho = blk & 63;
    int t = threadIdx.x, lane = t & 63, w = t >> 6;
    int r = lane & 15, kg = lane >> 4;
    int sR = (r >> 1) & 3;

    f32x4 acc[4][4];
    f32x4 zz = {0.f, 0.f, 0.f, 0.f};
#pragma unroll
    for (int m = 0; m < 4; ++m)
#pragma unroll
        for (int n = 0; n < 4; ++n) acc[m][n] = zz;

    const u16* abase = y1p + (size_t)(b * 64 + ho) * 16384;

    for (int ch = 0; ch < 8; ++ch) {
#pragma unroll
        for (int p = 0; p < 4; ++p) {
            int slot = p * 256 + t;
            int o = slot >> 2, qq = slot & 3;
            gld16(w1bf + o * 256 + ch * 32 + ((qq ^ ((o >> 1) & 3)) << 3),
                  smem + p * 4096 + (t >> 6) * 1024);
        }
        {
            int pix = t >> 2, qq = t & 3;
            gld16(abase + pix * 256 + ch * 32 + ((qq ^ ((pix >> 1) & 3)) << 3),
                  smem + 16384 + (t >> 6) * 1024);
        }
        __syncthreads();
        bf16x8 af[4], bfr[4];
#pragma unroll
        for (int m = 0; m < 4; ++m)
            af[m] = *(bf16x8*)(atile + (m * 16 + r) * 32 + ((kg ^ sR) << 3));
#pragma unroll
        for (int n = 0; n < 4; ++n)
            bfr[n] = *(bf16x8*)(btile + (w * 64 + n * 16 + r) * 32 + ((kg ^ sR) << 3));
#pragma unroll
        for (int m = 0; m < 4; ++m)
#pragma unroll
            for (int n = 0; n < 4; ++n)
                acc[m][n] = __builtin_amdgcn_mfma_f32_16x16x32_bf16(af[m], bfr[n], acc[m][n], 0, 0, 0);
        __syncthreads();
    }

    int rg = lane >> 4;
#pragma unroll
    for (int m = 0; m < 4; ++m)
#pragma unroll
        for (int n = 0; n < 4; ++n) {
            int o = w * 64 + n * 16 + r;
            int pix0 = m * 16 + rg * 4;
            float4 v;
            v.x = acc[m][n][0]; v.y = acc[m][n][1];
            v.z = acc[m][n][2]; v.w = acc[m][n][3];
            *(float4*)(out + ((size_t)(b * 256 + o) * 64 + ho) * 64 + pix0) = v;
        }
}

// ---------------- instance norm + leaky, in place on d_out ----------------
__global__ __launch_bounds__(256) void instnorm(float* __restrict__ out)
{
    int bc = blockIdx.x;
    float* p = out + (size_t)bc * 4096;
    int t = threadIdx.x;

    float4 v[4];
    float s1 = 0.f, s2 = 0.f;
#pragma unroll
    for (int i = 0; i < 4; ++i) {
        v[i] = *(const float4*)&p[(t + i * 256) * 4];
        s1 += v[i].x + v[i].y + v[i].z + v[i].w;
        s2 += v[i].x * v[i].x + v[i].y * v[i].y + v[i].z * v[i].z + v[i].w * v[i].w;
    }
#pragma unroll
    for (int o = 32; o > 0; o >>= 1) {
        s1 += __shfl_down(s1, o);
        s2 += __shfl_down(s2, o);
    }
    __shared__ float rs[8];
    __shared__ float mb[2];
    int wave = t >> 6;
    if ((t & 63) == 0) { rs[wave] = s1; rs[4 + wave] = s2; }
    __syncthreads();
    if (t == 0) {
        float a = rs[0] + rs[1] + rs[2] + rs[3];
        float qq = rs[4] + rs[5] + rs[6] + rs[7];
        float mean = a * (1.f / 4096.f);
        float var  = qq * (1.f / 4096.f) - mean * mean;
        mb[0] = mean;
        mb[1] = rsqrtf(var + 1e-5f);
    }
    __syncthreads();
    float mean = mb[0], inv = mb[1];
#pragma unroll
    for (int i = 0; i < 4; ++i) {
        float4 u = v[i];
        u.x = lrelu((u.x - mean) * inv);
        u.y = lrelu((u.y - mean) * inv);
        u.z = lrelu((u.z - mean) * inv);
        u.w = lrelu((u.w - mean) * inv);
        *(float4*)&p[(t + i * 256) * 4] = u;
    }
}

extern "C" void kernel_launch(void* const* d_in, const int* in_sizes, int n_in,
                              void* d_out, int out_size, void* d_ws, size_t ws_size,
                              hipStream_t stream)
{
    const float* x     = (const float*)d_in[0];
    const float* w_off = (const float*)d_in[1];
    const float* w_def = (const float*)d_in[2];
    const float* w1    = (const float*)d_in[3];
    float* out = (float*)d_out;
    float* ws  = (float*)d_ws;

    float* off    = ws + OFF_OFS;
    u16*   wdefbf = (u16*)(ws + WDEF_OFS);
    u16*   w1bf   = (u16*)(ws + W1_OFS);
    u16*   y1p    = (u16*)(ws + Y1_OFS);
    float* part   = ws + PART_OFS;

    hipLaunchKernelGGL(prep,            dim3(2304), dim3(256), 0, stream, w_def, w1, wdefbf, w1bf);
    hipLaunchKernelGGL(offconv_partial, dim3(2048), dim3(256), 0, stream, x, w_off, part);
    hipLaunchKernelGGL(reduce_off,      dim3(576),  dim3(256), 0, stream, part, off);
    hipLaunchKernelGGL(deform_mfma,     dim3(512),  dim3(256), 0, stream, x, off, wdefbf, y1p);
    hipLaunchKernelGGL(conv1x1_mfma,    dim3(512),  dim3(256), 0, stream, y1p, w1bf, out);
    hipLaunchKernelGGL(instnorm,        dim3(2048), dim3(256), 0, stream, out);
}

// Round 4
// 508.101 us; speedup vs baseline: 2.5171x; 1.1655x over previous
//
#include <hip/hip_runtime.h>

#define B_   8
#define CIN  256
#define H_   128
#define W_   128
#define HO   64
#define WO   64
#define CO_  256
#define NEG  0.2f

typedef __attribute__((ext_vector_type(8))) short bf16x8;
typedef __attribute__((ext_vector_type(4))) float f32x4;
typedef unsigned short u16;

// ws layout (float slots):
//  off    : [8][18][64][64] f32            @ 0        (589824)
//  wdefbf : [9][8][256][32] bf16           @ 589824   (294912 slots)
//  w1bf   : [256][256] bf16                @ 884736   (32768 slots)
//  y1p    : [8][64][64][256] bf16          @ 917504   (4194304 slots)
//  part   : [4][8][18][64][64] f32         @ 917504   (2359296 slots, ALIASES y1p;
//                                                      dead before deform writes y1p)
#define OFF_OFS   0
#define WDEF_OFS  589824
#define W1_OFS    884736
#define Y1_OFS    917504
#define PART_OFS  917504

__device__ __forceinline__ float lrelu(float v) { return v >= 0.f ? v : NEG * v; }

__device__ __forceinline__ u16 f2bf(float f) {
    unsigned u = __float_as_uint(f);
    u += 0x7FFFu + ((u >> 16) & 1u);   // RNE
    return (u16)(u >> 16);
}

__device__ __forceinline__ void gld16(const void* g, void* l) {
    __builtin_amdgcn_global_load_lds((const __attribute__((address_space(1))) unsigned*)g,
                                     (__attribute__((address_space(3))) unsigned*)l, 16, 0, 0);
}

// ---------------- one-time weight prep: transpose + bf16 ----------------
__global__ __launch_bounds__(256) void prep(
    const float* __restrict__ wdef, const float* __restrict__ w1,
    u16* __restrict__ wdefbf, u16* __restrict__ w1bf)
{
    int i = blockIdx.x * 256 + threadIdx.x;
    if (i < 9 * 8 * 256 * 32) {
        int cc = i & 31;
        int co = (i >> 5) & 255;
        int ch = (i >> 13) & 7;
        int k  = i >> 16;
        wdefbf[i] = f2bf(wdef[((size_t)co * 256 + ch * 32 + cc) * 9 + k]);
    }
    if (i < 65536) w1bf[i] = f2bf(w1[i]);
}

// ---------------- offset conv: thread = (wo, ci-subchunk), all 18 co in regs ----------------
// grid 2048: (b, g, ho). Block's 4 sub-groups s cover ci [64g+16s, 64g+16s+16).
// No duplicated x gathers (was 4x); 162 unrolled FMAs hide each 9-load batch.
__global__ __launch_bounds__(256) void offconv_partial(
    const float* __restrict__ x, const float* __restrict__ w_off,
    float* __restrict__ part)
{
    __shared__ float red[4][18][64];   // 18 KB

    int bid = blockIdx.x;
    int swz = (bid & 7) * 256 + (bid >> 3);   // XCD owns one b
    int b  = swz >> 8;
    int g  = (swz >> 6) & 3;
    int ho = swz & 63;
    int t  = threadIdx.x;
    int wo = t & 63;
    int s  = t >> 6;

    float acc[18];
#pragma unroll
    for (int co = 0; co < 18; ++co) acc[co] = 0.f;

    const float* xb = x + (size_t)b * CIN * H_ * W_;
    int ci0 = g * 64 + s * 16;

#pragma unroll 2
    for (int ci = ci0; ci < ci0 + 16; ++ci) {
        const float* xp = xb + (size_t)ci * (H_ * W_);
        float xv[9];
#pragma unroll
        for (int ky = 0; ky < 3; ++ky) {
            int y = ho * 2 - 1 + ky;
            bool vy = (unsigned)y < (unsigned)H_;
#pragma unroll
            for (int kx = 0; kx < 3; ++kx) {
                int xc = wo * 2 - 1 + kx;
                xv[ky * 3 + kx] = (vy && (unsigned)xc < (unsigned)W_) ? xp[y * W_ + xc] : 0.f;
            }
        }
        const float* wp = w_off + (size_t)ci * 9;
#pragma unroll
        for (int co = 0; co < 18; ++co) {
            const float* wc = wp + (size_t)co * 2304;
#pragma unroll
            for (int q = 0; q < 9; ++q) acc[co] += xv[q] * wc[q];
        }
    }

    // cross-subgroup reduction via LDS
#pragma unroll
    for (int co = 0; co < 18; ++co) red[s][co][wo] = acc[co];
    __syncthreads();

    for (int i = t; i < 18 * 64; i += 256) {
        int co = i >> 6, w2 = i & 63;
        float v = red[0][co][w2] + red[1][co][w2] + red[2][co][w2] + red[3][co][w2];
        part[(((size_t)(g * 8 + b) * 18 + co) * HO + ho) * WO + w2] = v;
    }
}

// sum the 4 partials -> off  (589824 floats = 147456 float4)
__global__ __launch_bounds__(256) void reduce_off(
    const float* __restrict__ part, float* __restrict__ off)
{
    int i4 = blockIdx.x * 256 + threadIdx.x;
    if (i4 >= 147456) return;
    float4 a = *(const float4*)&part[(size_t)i4 * 4];
    float4 b = *(const float4*)&part[(size_t)i4 * 4 + 589824];
    float4 c = *(const float4*)&part[(size_t)i4 * 4 + 2 * 589824];
    float4 d = *(const float4*)&part[(size_t)i4 * 4 + 3 * 589824];
    float4 o;
    o.x = (a.x + b.x) + (c.x + d.x);
    o.y = (a.y + b.y) + (c.y + d.y);
    o.z = (a.z + b.z) + (c.z + d.z);
    o.w = (a.w + b.w) + (c.w + d.w);
    *(float4*)&off[(size_t)i4 * 4] = o;
}

// ---------------- deformable conv: bilinear sample -> bf16 MFMA GEMM ----------------
__global__ __launch_bounds__(256) void deform_mfma(
    const float* __restrict__ x, const float* __restrict__ off,
    const u16* __restrict__ wdefbf, u16* __restrict__ y1p)
{
    __shared__ __align__(16) char smem[33792];
    u16*   wtile = (u16*)smem;              // [256][32] bf16, quarter-swizzled
    u16*   samp  = (u16*)(smem + 16384);    // [64][32]  bf16, quarter-swizzled
    int*   lofs  = (int*)(smem + 20480);    // [64][4]
    float* lw    = (float*)(smem + 21504);  // [64][4]
    u16*   outT  = (u16*)smem;              // [64][256] epilogue alias (32KB)

    int blk = blockIdx.x;
    blk = (blk & 7) * 64 + (blk >> 3);      // XCD swizzle
    int b = blk >> 6, ho = blk & 63;
    int t = threadIdx.x;
    int lane = t & 63, w = t >> 6;
    int pix = t & 63;
    int q   = t >> 6;

    f32x4 acc[4][4];
    f32x4 zz = {0.f, 0.f, 0.f, 0.f};
#pragma unroll
    for (int m = 0; m < 4; ++m)
#pragma unroll
        for (int n = 0; n < 4; ++n) acc[m][n] = zz;

    const float* xb = x + (size_t)b * (CIN * H_ * W_);
    int r  = lane & 15;
    int kg = lane >> 4;
    int sA = (pix >> 1) & 3;
    int sR = (r >> 1) & 3;

    for (int k = 0; k < 9; ++k) {
        int ky = k / 3, kx = k - 3 * ky;
        if (t < 64) {
            int wo = t;
            float dy = off[(((size_t)b * 18 + 2 * k    ) * HO + ho) * WO + wo];
            float dx = off[(((size_t)b * 18 + 2 * k + 1) * HO + ho) * WO + wo];
            float py = (float)(ho * 2 - 1 + ky) + dy;
            float px = (float)(wo * 2 - 1 + kx) + dx;
            float y0f = floorf(py), x0f = floorf(px);
            int y0 = (int)y0f, x0i = (int)x0f;
            float wy1 = py - y0f, wx1 = px - x0f;
            float wy0 = 1.f - wy1, wx0 = 1.f - wx1;
            int y1i = y0 + 1, x1i = x0i + 1;
            bool vy0 = (unsigned)y0  < (unsigned)H_;
            bool vy1 = (unsigned)y1i < (unsigned)H_;
            bool vx0 = (unsigned)x0i < (unsigned)W_;
            bool vx1 = (unsigned)x1i < (unsigned)W_;
            int yc0 = min(max(y0, 0), H_ - 1), yc1 = min(max(y1i, 0), H_ - 1);
            int xc0 = min(max(x0i, 0), W_ - 1), xc1 = min(max(x1i, 0), W_ - 1);
            lofs[wo * 4 + 0] = yc0 * W_ + xc0;
            lofs[wo * 4 + 1] = yc0 * W_ + xc1;
            lofs[wo * 4 + 2] = yc1 * W_ + xc0;
            lofs[wo * 4 + 3] = yc1 * W_ + xc1;
            lw[wo * 4 + 0] = (vy0 && vx0) ? wy0 * wx0 : 0.f;
            lw[wo * 4 + 1] = (vy0 && vx1) ? wy0 * wx1 : 0.f;
            lw[wo * 4 + 2] = (vy1 && vx0) ? wy1 * wx0 : 0.f;
            lw[wo * 4 + 3] = (vy1 && vx1) ? wy1 * wx1 : 0.f;
        }
        __syncthreads();
        int   o00 = lofs[pix * 4 + 0], o01 = lofs[pix * 4 + 1];
        int   o10 = lofs[pix * 4 + 2], o11 = lofs[pix * 4 + 3];
        float f00 = lw[pix * 4 + 0],   f01 = lw[pix * 4 + 1];
        float f10 = lw[pix * 4 + 2],   f11 = lw[pix * 4 + 3];

        const u16* wk = wdefbf + ((size_t)k << 16);
        for (int ch = 0; ch < 8; ++ch) {
            const u16* wsrc = wk + (ch << 13);
#pragma unroll
            for (int p = 0; p < 4; ++p) {
                int slot = p * 256 + t;
                int co = slot >> 2, qq = slot & 3;
                gld16(wsrc + co * 32 + ((qq ^ ((co >> 1) & 3)) << 3),
                      smem + p * 4096 + (t >> 6) * 1024);
            }
            bf16x8 sv;
#pragma unroll
            for (int j = 0; j < 8; ++j) {
                int c = ch * 32 + q * 8 + j;
                const float* xq = xb + (size_t)c * (H_ * W_);
                float v = xq[o00] * f00 + xq[o01] * f01 + xq[o10] * f10 + xq[o11] * f11;
                sv[j] = (short)f2bf(v);
            }
            *(bf16x8*)(samp + pix * 32 + ((q ^ sA) << 3)) = sv;
            __syncthreads();

            bf16x8 af[4], bfr[4];
#pragma unroll
            for (int m = 0; m < 4; ++m)
                af[m] = *(bf16x8*)(samp + (m * 16 + r) * 32 + ((kg ^ sR) << 3));
#pragma unroll
            for (int n = 0; n < 4; ++n)
                bfr[n] = *(bf16x8*)(wtile + (w * 64 + n * 16 + r) * 32 + ((kg ^ sR) << 3));
#pragma unroll
            for (int m = 0; m < 4; ++m)
#pragma unroll
                for (int n = 0; n < 4; ++n)
                    acc[m][n] = __builtin_amdgcn_mfma_f32_16x16x32_bf16(af[m], bfr[n], acc[m][n], 0, 0, 0);
            __syncthreads();
        }
    }

    int rg = lane >> 4;
#pragma unroll
    for (int m = 0; m < 4; ++m)
#pragma unroll
        for (int n = 0; n < 4; ++n) {
            int co = w * 64 + n * 16 + r;
#pragma unroll
            for (int j = 0; j < 4; ++j) {
                int prow = m * 16 + rg * 4 + j;
                outT[prow * 256 + co] = f2bf(lrelu(acc[m][n][j]));
            }
        }
    __syncthreads();
    u16* dst = y1p + (size_t)(b * 64 + ho) * 16384;
#pragma unroll
    for (int j = 0; j < 8; ++j)
        *(int4*)((char*)dst + j * 4096 + t * 16) = *(int4*)(smem + j * 4096 + t * 16);
}

// ---------------- 1x1 conv: bf16 MFMA ----------------
__global__ __launch_bounds__(256) void conv1x1_mfma(
    const u16* __restrict__ y1p, const u16* __restrict__ w1bf,
    float* __restrict__ out)
{
    __shared__ __align__(16) char smem[20480];
    u16* btile = (u16*)smem;
    u16* atile = (u16*)(smem + 16384);

    int blk = blockIdx.x;
    blk = (blk & 7) * 64 + (blk >> 3);
    int b = blk >> 6, ho = blk & 63;
    int t = threadIdx.x, lane = t & 63, w = t >> 6;
    int r = lane & 15, kg = lane >> 4;
    int sR = (r >> 1) & 3;

    f32x4 acc[4][4];
    f32x4 zz = {0.f, 0.f, 0.f, 0.f};
#pragma unroll
    for (int m = 0; m < 4; ++m)
#pragma unroll
        for (int n = 0; n < 4; ++n) acc[m][n] = zz;

    const u16* abase = y1p + (size_t)(b * 64 + ho) * 16384;

    for (int ch = 0; ch < 8; ++ch) {
#pragma unroll
        for (int p = 0; p < 4; ++p) {
            int slot = p * 256 + t;
            int o = slot >> 2, qq = slot & 3;
            gld16(w1bf + o * 256 + ch * 32 + ((qq ^ ((o >> 1) & 3)) << 3),
                  smem + p * 4096 + (t >> 6) * 1024);
        }
        {
            int pix = t >> 2, qq = t & 3;
            gld16(abase + pix * 256 + ch * 32 + ((qq ^ ((pix >> 1) & 3)) << 3),
                  smem + 16384 + (t >> 6) * 1024);
        }
        __syncthreads();
        bf16x8 af[4], bfr[4];
#pragma unroll
        for (int m = 0; m < 4; ++m)
            af[m] = *(bf16x8*)(atile + (m * 16 + r) * 32 + ((kg ^ sR) << 3));
#pragma unroll
        for (int n = 0; n < 4; ++n)
            bfr[n] = *(bf16x8*)(btile + (w * 64 + n * 16 + r) * 32 + ((kg ^ sR) << 3));
#pragma unroll
        for (int m = 0; m < 4; ++m)
#pragma unroll
            for (int n = 0; n < 4; ++n)
                acc[m][n] = __builtin_amdgcn_mfma_f32_16x16x32_bf16(af[m], bfr[n], acc[m][n], 0, 0, 0);
        __syncthreads();
    }

    int rg = lane >> 4;
#pragma unroll
    for (int m = 0; m < 4; ++m)
#pragma unroll
        for (int n = 0; n < 4; ++n) {
            int o = w * 64 + n * 16 + r;
            int pix0 = m * 16 + rg * 4;
            float4 v;
            v.x = acc[m][n][0]; v.y = acc[m][n][1];
            v.z = acc[m][n][2]; v.w = acc[m][n][3];
            *(float4*)(out + ((size_t)(b * 256 + o) * 64 + ho) * 64 + pix0) = v;
        }
}

// ---------------- instance norm + leaky, in place on d_out ----------------
__global__ __launch_bounds__(256) void instnorm(float* __restrict__ out)
{
    int bc = blockIdx.x;
    float* p = out + (size_t)bc * 4096;
    int t = threadIdx.x;

    float4 v[4];
    float s1 = 0.f, s2 = 0.f;
#pragma unroll
    for (int i = 0; i < 4; ++i) {
        v[i] = *(const float4*)&p[(t + i * 256) * 4];
        s1 += v[i].x + v[i].y + v[i].z + v[i].w;
        s2 += v[i].x * v[i].x + v[i].y * v[i].y + v[i].z * v[i].z + v[i].w * v[i].w;
    }
#pragma unroll
    for (int o = 32; o > 0; o >>= 1) {
        s1 += __shfl_down(s1, o);
        s2 += __shfl_down(s2, o);
    }
    __shared__ float rs[8];
    __shared__ float mb[2];
    int wave = t >> 6;
    if ((t & 63) == 0) { rs[wave] = s1; rs[4 + wave] = s2; }
    __syncthreads();
    if (t == 0) {
        float a = rs[0] + rs[1] + rs[2] + rs[3];
        float qq = rs[4] + rs[5] + rs[6] + rs[7];
        float mean = a * (1.f / 4096.f);
        float var  = qq * (1.f / 4096.f) - mean * mean;
        mb[0] = mean;
        mb[1] = rsqrtf(var + 1e-5f);
    }
    __syncthreads();
    float mean = mb[0], inv = mb[1];
#pragma unroll
    for (int i = 0; i < 4; ++i) {
        float4 u = v[i];
        u.x = lrelu((u.x - mean) * inv);
        u.y = lrelu((u.y - mean) * inv);
        u.z = lrelu((u.z - mean) * inv);
        u.w = lrelu((u.w - mean) * inv);
        *(float4*)&p[(t + i * 256) * 4] = u;
    }
}

extern "C" void kernel_launch(void* const* d_in, const int* in_sizes, int n_in,
                              void* d_out, int out_size, void* d_ws, size_t ws_size,
                              hipStream_t stream)
{
    const float* x     = (const float*)d_in[0];
    const float* w_off = (const float*)d_in[1];
    const float* w_def = (const float*)d_in[2];
    const float* w1    = (const float*)d_in[3];
    float* out = (float*)d_out;
    float* ws  = (float*)d_ws;

    float* off    = ws + OFF_OFS;
    u16*   wdefbf = (u16*)(ws + WDEF_OFS);
    u16*   w1bf   = (u16*)(ws + W1_OFS);
    u16*   y1p    = (u16*)(ws + Y1_OFS);
    float* part   = ws + PART_OFS;

    hipLaunchKernelGGL(prep,            dim3(2304), dim3(256), 0, stream, w_def, w1, wdefbf, w1bf);
    hipLaunchKernelGGL(offconv_partial, dim3(2048), dim3(256), 0, stream, x, w_off, part);
    hipLaunchKernelGGL(reduce_off,      dim3(576),  dim3(256), 0, stream, part, off);
    hipLaunchKernelGGL(deform_mfma,     dim3(512),  dim3(256), 0, stream, x, off, wdefbf, y1p);
    hipLaunchKernelGGL(conv1x1_mfma,    dim3(512),  dim3(256), 0, stream, y1p, w1bf, out);
    hipLaunchKernelGGL(instnorm,        dim3(2048), dim3(256), 0, stream, out);
}